// Round 7
// baseline (103.111 us; speedup 1.0000x reference)
//
#include <hip/hip_runtime.h>

#define N 8192
#define D 64
#define GRAM_BLOCKS 256
#define APPLY_BLOCKS 1024

// Kernel 1: G = S^T S (64x64) and t = colsum(S), register-tiled outer products.
// Thread (ty,tx) in a 16x16 grid owns G[4ty..4ty+3][4tx..4tx+3].
// 256 blocks x 32 rows: full CU coverage; unroll 8 keeps 16 loads in flight.
__global__ __launch_bounds__(256) void gram_kernel(const float* __restrict__ S,
                                                   float* __restrict__ G,
                                                   float* __restrict__ t) {
    const int tid = threadIdx.x;
    const int ty = tid >> 4;                 // 0..15
    const int tx = tid & 15;                 // 0..15

    float acc[4][4];
#pragma unroll
    for (int i = 0; i < 4; ++i)
#pragma unroll
        for (int j = 0; j < 4; ++j) acc[i][j] = 0.f;
    float tac[4] = {0.f, 0.f, 0.f, 0.f};

    const int rpb = N / GRAM_BLOCKS;         // 32 rows per block
    const int r0 = blockIdx.x * rpb;
    const float* Sa = S + (size_t)r0 * D + 4 * ty;
    const float* Sb = S + (size_t)r0 * D + 4 * tx;

#pragma unroll 8
    for (int r = 0; r < rpb; ++r) {
        const float4 a = *(const float4*)(Sa + (size_t)r * D);
        const float4 b = *(const float4*)(Sb + (size_t)r * D);
        const float av[4] = {a.x, a.y, a.z, a.w};
        const float bv[4] = {b.x, b.y, b.z, b.w};
#pragma unroll
        for (int i = 0; i < 4; ++i)
#pragma unroll
            for (int j = 0; j < 4; ++j) acc[i][j] += av[i] * bv[j];
        if (ty == 0) {
#pragma unroll
            for (int j = 0; j < 4; ++j) tac[j] += bv[j];
        }
    }

#pragma unroll
    for (int i = 0; i < 4; ++i)
#pragma unroll
        for (int j = 0; j < 4; ++j)
            atomicAdd(&G[(4 * ty + i) * D + 4 * tx + j], acc[i][j]);
    if (ty == 0) {
#pragma unroll
        for (int j = 0; j < 4; ++j) atomicAdd(&t[4 * tx + j], tac[j]);
    }
}

// Kernel 2: out[i,:] = (s_i @ G) / (s_i . t). One row-PAIR per wave
// (2 indep FMA chains sharing Gs reads); denominator via 6-step butterfly.
// 1024 blocks -> 4 blocks/CU -> 2 waves/SIMD for latency hiding.
__global__ __launch_bounds__(256) void apply_kernel(const float* __restrict__ S,
                                                    const float* __restrict__ G,
                                                    const float* __restrict__ t,
                                                    float* __restrict__ out) {
    __shared__ float Gs[D * D];
    __shared__ float ts[D];
    const int tid = threadIdx.x;
#pragma unroll
    for (int i = tid; i < (D * D) / 4; i += 256)
        ((float4*)Gs)[i] = ((const float4*)G)[i];
    if (tid < D) ts[tid] = t[tid];
    __syncthreads();

    const int lane = tid & 63;
    const int wid = tid >> 6;
    const float tl = ts[lane];

    const int ia = (blockIdx.x * 4 + wid) * 2;        // 2 rows per wave
    const int ib = ia + 1;
    const float va = S[(size_t)ia * D + lane];
    const float vb = S[(size_t)ib * D + lane];

    // denominators: rs = dot(v, t), butterfly-reduced, result in all lanes
    float pa = va * tl, pb = vb * tl;
#pragma unroll
    for (int s = 1; s < 64; s <<= 1) {
        pa += __shfl_xor(pa, s, 64);
        pb += __shfl_xor(pb, s, 64);
    }

    float aa = 0.f, ab = 0.f;
#pragma unroll
    for (int k = 0; k < D; ++k) {
        const float g = Gs[k * D + lane];             // stride-1: conflict-free
        aa += __shfl(va, k, 64) * g;                  // constant lane -> readlane
        ab += __shfl(vb, k, 64) * g;
    }
    out[(size_t)ia * D + lane] = aa / pa;
    out[(size_t)ib * D + lane] = ab / pb;
}

extern "C" void kernel_launch(void* const* d_in, const int* in_sizes, int n_in,
                              void* d_out, int out_size, void* d_ws, size_t ws_size,
                              hipStream_t stream) {
    const float* S = (const float*)d_in[0];
    float* out = (float*)d_out;
    float* G = (float*)d_ws;
    float* t = G + D * D;

    hipMemsetAsync(d_ws, 0, (D * D + D) * sizeof(float), stream);
    gram_kernel<<<GRAM_BLOCKS, 256, 0, stream>>>(S, G, t);
    apply_kernel<<<APPLY_BLOCKS, 256, 0, stream>>>(S, G, t, out);
}

// Round 8
// 84.948 us; speedup vs baseline: 1.2138x; 1.2138x over previous
//
#include <hip/hip_runtime.h>

#define N 8192
#define D 64
#define P 64                      // number of partial Gram copies
#define SLICE (D * D + D)         // 4160 floats per partial (G then t)
#define SLICE4 (SLICE / 4)        // 1040 float4s

// Kernel 1: per-block partial G = S_blk^T S_blk and t = colsum, register-tiled.
// Thread (ty,tx) owns G[4ty..4ty+3][4tx..4tx+3]. Plain float4 stores to a
// private ws slice — zero atomics, zero cross-block contention.
__global__ __launch_bounds__(256) void gram_partial(const float* __restrict__ S,
                                                    float* __restrict__ ws) {
    const int tid = threadIdx.x;
    const int ty = tid >> 4;                 // 0..15
    const int tx = tid & 15;                 // 0..15

    float acc[4][4];
#pragma unroll
    for (int i = 0; i < 4; ++i)
#pragma unroll
        for (int j = 0; j < 4; ++j) acc[i][j] = 0.f;
    float tac[4] = {0.f, 0.f, 0.f, 0.f};

    const int rpb = N / P;                   // 128 rows per block
    const int r0 = blockIdx.x * rpb;
    const float* Sa = S + (size_t)r0 * D + 4 * ty;
    const float* Sb = S + (size_t)r0 * D + 4 * tx;

#pragma unroll 8
    for (int r = 0; r < rpb; ++r) {
        const float4 a = *(const float4*)(Sa + (size_t)r * D);
        const float4 b = *(const float4*)(Sb + (size_t)r * D);
        const float av[4] = {a.x, a.y, a.z, a.w};
        const float bv[4] = {b.x, b.y, b.z, b.w};
#pragma unroll
        for (int i = 0; i < 4; ++i)
#pragma unroll
            for (int j = 0; j < 4; ++j) acc[i][j] += av[i] * bv[j];
        if (ty == 0) {
#pragma unroll
            for (int j = 0; j < 4; ++j) tac[j] += bv[j];
        }
    }

    float* pw = ws + (size_t)blockIdx.x * SLICE;
#pragma unroll
    for (int i = 0; i < 4; ++i)
        *(float4*)(pw + (4 * ty + i) * D + 4 * tx) =
            make_float4(acc[i][0], acc[i][1], acc[i][2], acc[i][3]);
    if (ty == 0)
        *(float4*)(pw + D * D + 4 * tx) =
            make_float4(tac[0], tac[1], tac[2], tac[3]);
}

// Kernel 2: sum the P partial slices -> final G,t at ws + P*SLICE.
// Thread handles one float4 of the slice; reads coalesced across threads.
__global__ __launch_bounds__(256) void reduce_kernel(float* __restrict__ ws) {
    const float4* src = (const float4*)ws;
    float4* dst = (float4*)(ws + (size_t)P * SLICE);
    const int gid = blockIdx.x * 256 + threadIdx.x;
    for (int i4 = gid; i4 < SLICE4; i4 += 1024) {
        float4 acc = make_float4(0.f, 0.f, 0.f, 0.f);
#pragma unroll 8
        for (int p = 0; p < P; ++p) {
            const float4 v = src[(size_t)p * SLICE4 + i4];
            acc.x += v.x; acc.y += v.y; acc.z += v.z; acc.w += v.w;
        }
        dst[i4] = acc;
    }
}

// Kernel 3: out[i,:] = (s_i @ G) / (s_i . t). One row-pair per wave
// (2 indep FMA chains sharing Gs reads); denominator via 6-step butterfly.
__global__ __launch_bounds__(256) void apply_kernel(const float* __restrict__ S,
                                                    const float* __restrict__ G,
                                                    const float* __restrict__ t,
                                                    float* __restrict__ out) {
    __shared__ float Gs[D * D];
    __shared__ float ts[D];
    const int tid = threadIdx.x;
#pragma unroll
    for (int i = tid; i < (D * D) / 4; i += 256)
        ((float4*)Gs)[i] = ((const float4*)G)[i];
    if (tid < D) ts[tid] = t[tid];
    __syncthreads();

    const int lane = tid & 63;
    const int wid = tid >> 6;
    const float tl = ts[lane];

    const int ia = (blockIdx.x * 4 + wid) * 2;        // 2 rows per wave
    const int ib = ia + 1;
    const float va = S[(size_t)ia * D + lane];
    const float vb = S[(size_t)ib * D + lane];

    float pa = va * tl, pb = vb * tl;
#pragma unroll
    for (int s = 1; s < 64; s <<= 1) {
        pa += __shfl_xor(pa, s, 64);
        pb += __shfl_xor(pb, s, 64);
    }

    float aa = 0.f, ab = 0.f;
#pragma unroll
    for (int k = 0; k < D; ++k) {
        const float g = Gs[k * D + lane];             // stride-1: conflict-free
        aa += __shfl(va, k, 64) * g;                  // constant lane -> readlane
        ab += __shfl(vb, k, 64) * g;
    }
    out[(size_t)ia * D + lane] = aa / pa;
    out[(size_t)ib * D + lane] = ab / pb;
}

extern "C" void kernel_launch(void* const* d_in, const int* in_sizes, int n_in,
                              void* d_out, int out_size, void* d_ws, size_t ws_size,
                              hipStream_t stream) {
    const float* S = (const float*)d_in[0];
    float* out = (float*)d_out;
    float* ws = (float*)d_ws;
    float* Gfin = ws + (size_t)P * SLICE;
    float* tfin = Gfin + D * D;

    gram_partial<<<P, 256, 0, stream>>>(S, ws);
    reduce_kernel<<<4, 256, 0, stream>>>(ws);
    apply_kernel<<<1024, 256, 0, stream>>>(S, Gfin, tfin, out);
}